// Round 8
// baseline (260.032 us; speedup 1.0000x reference)
//
#include <hip/hip_runtime.h>
#include <hip/hip_bf16.h>

#define B 32
#define C 512
#define HW 3136            // 56*56 floats per plane
#define HW4 784            // fx4 per plane
#define TH 0.01f
#define NPG 16             // blocks (partial groups) per batch
#define CPB 32             // channels per block
#define CPW 8              // channels per wave

typedef float fx4 __attribute__((ext_vector_type(4)));

// Zero the 64 sync counters each call (d_ws poisoned 0xAA once, not re-poisoned).
__global__ void init_kernel(int* __restrict__ counters) {
    if (threadIdx.x < 64) counters[threadIdx.x] = 0;
}

__device__ __forceinline__ float epi(float s, float wc, float scale, float wf, float z) {
    const float fm = s * wc;
    return (fm > TH) ? 1.0f - wf / (1.0f + __expf(-scale * fm)) : z;
}

// ---------------------------------------------------------------------------
// Single resident kernel, 3 phases, per-b spin sync.
// 512 blocks, 50 KB LDS, <=168 VGPR -> 3 blocks/CU -> all 512 co-resident.
// ---------------------------------------------------------------------------
__global__ __launch_bounds__(256, 3) void fused_kernel(const float* __restrict__ x,
                                                       const float* __restrict__ w,
                                                       const float* __restrict__ scale_p,
                                                       const float* __restrict__ wf_p,
                                                       float* __restrict__ out,
                                                       float* __restrict__ sal,
                                                       int* __restrict__ cA,
                                                       int* __restrict__ cB) {
    const int bid = blockIdx.x;
    const int b   = bid >> 4;            // /NPG
    const int pg  = bid & (NPG - 1);
    const int t   = threadIdx.x;
    const int l   = t & 63;
    const int wv  = t >> 6;

    __shared__ float lds[4 * HW];        // 50176 B

    // ---------------- phase 1: partial saliency over CPB channels ----------
    const float* __restrict__ xb = x + (size_t)b * C * HW;
    fx4 acc[12];
    float acct = 0.f;
    #pragma unroll
    for (int j = 0; j < 12; ++j) acc[j] = (fx4)0.f;

    const int cbase = pg * CPB + wv * CPW;
    for (int i = 0; i < CPW; ++i) {
        const float* __restrict__ pf = xb + (size_t)(cbase + i) * HW;
        const fx4*   __restrict__ p4 = (const fx4*)pf;
        fx4 v[12];
        #pragma unroll
        for (int j = 0; j < 12; ++j) v[j] = __builtin_nontemporal_load(p4 + l + 64 * j);
        const float vt = __builtin_nontemporal_load(pf + 3072 + l);

        float ps[12];
        #pragma unroll
        for (int j = 0; j < 12; ++j) ps[j] = (v[j].x + v[j].y) + (v[j].z + v[j].w);
        float s = ((ps[0] + ps[1]) + (ps[2] + ps[3])) +
                  ((ps[4] + ps[5]) + (ps[6] + ps[7])) +
                  ((ps[8] + ps[9]) + (ps[10] + ps[11])) + vt;
        #pragma unroll
        for (int off = 1; off < 64; off <<= 1) s += __shfl_xor(s, off);
        const float a = s * (1.0f / (float)HW);   // alpha[b,c]

        #pragma unroll
        for (int j = 0; j < 12; ++j) acc[j] += v[j] * a;
        acct += vt * a;
    }

    // dump per-wave acc into its linear LDS region
    float* reg = lds + wv * HW;
    #pragma unroll
    for (int j = 0; j < 12; ++j) ((fx4*)reg)[l + 64 * j] = acc[j];
    reg[3072 + l] = acct;
    __syncthreads();

    // cooperative 4-region sum -> partial plane (cached store, d_out plane pg)
    float* __restrict__ pdst = out + (size_t)b * C * HW + (size_t)pg * HW;
    for (int i = t; i < HW4; i += 256) {
        fx4 r = ((const fx4*)lds)[i];
        r += ((const fx4*)(lds + HW))[i];
        r += ((const fx4*)(lds + 2 * HW))[i];
        r += ((const fx4*)(lds + 3 * HW))[i];
        ((fx4*)pdst)[i] = r;
    }
    __threadfence();
    __syncthreads();
    if (t == 0) {
        atomicAdd(&cA[b], 1);
        while (__hip_atomic_load(&cA[b], __ATOMIC_ACQUIRE, __HIP_MEMORY_SCOPE_AGENT) < NPG)
            __builtin_amdgcn_s_sleep(2);
    }
    __syncthreads();

    // ---------------- phase 2: sal slice (196 floats) -----------------------
    if (t < 196) {
        const int f = pg * 196 + t;
        const float* __restrict__ pbase = out + (size_t)b * C * HW + f;
        float ssum = 0.f;
        #pragma unroll
        for (int g = 0; g < NPG; ++g) ssum += pbase[(size_t)g * HW];
        sal[b * HW + f] = ssum * (1.0f / (float)C);
    }
    __threadfence();
    __syncthreads();
    if (t == 0) {
        atomicAdd(&cB[b], 1);
        while (__hip_atomic_load(&cB[b], __ATOMIC_ACQUIRE, __HIP_MEMORY_SCOPE_AGENT) < NPG)
            __builtin_amdgcn_s_sleep(2);
    }
    __syncthreads();

    // ---------------- phase 3: expansion, co in [32pg, 32pg+32) -------------
    const fx4* __restrict__ salv = (const fx4*)(sal + (size_t)b * HW);
    const fx4 s0 = salv[t];
    const fx4 s1 = salv[256 + t];
    const fx4 s2 = salv[512 + t];
    fx4 s3 = (fx4)0.f;
    if (t < 16) s3 = salv[768 + t];

    const float scale = scale_p[0];
    const float wf    = wf_p[0];
    const float z     = 1.0f - 0.5f * wf;      // fm == 0 path

    fx4* __restrict__ ob =
        (fx4*)(out + (size_t)b * C * HW + (size_t)(pg * 32) * HW);

    for (int co = 0; co < 32; ++co) {
        const float wc = w[pg * 32 + co];
        fx4 r;
        r.x = epi(s0.x, wc, scale, wf, z); r.y = epi(s0.y, wc, scale, wf, z);
        r.z = epi(s0.z, wc, scale, wf, z); r.w = epi(s0.w, wc, scale, wf, z);
        __builtin_nontemporal_store(r, ob + (size_t)co * HW4 + t);
        r.x = epi(s1.x, wc, scale, wf, z); r.y = epi(s1.y, wc, scale, wf, z);
        r.z = epi(s1.z, wc, scale, wf, z); r.w = epi(s1.w, wc, scale, wf, z);
        __builtin_nontemporal_store(r, ob + (size_t)co * HW4 + 256 + t);
        r.x = epi(s2.x, wc, scale, wf, z); r.y = epi(s2.y, wc, scale, wf, z);
        r.z = epi(s2.z, wc, scale, wf, z); r.w = epi(s2.w, wc, scale, wf, z);
        __builtin_nontemporal_store(r, ob + (size_t)co * HW4 + 512 + t);
        if (t < 16) {
            r.x = epi(s3.x, wc, scale, wf, z); r.y = epi(s3.y, wc, scale, wf, z);
            r.z = epi(s3.z, wc, scale, wf, z); r.w = epi(s3.w, wc, scale, wf, z);
            __builtin_nontemporal_store(r, ob + (size_t)co * HW4 + 768 + t);
        }
    }
}

extern "C" void kernel_launch(void* const* d_in, const int* in_sizes, int n_in,
                              void* d_out, int out_size, void* d_ws, size_t ws_size,
                              hipStream_t stream) {
    const float* x      = (const float*)d_in[0];
    const float* conv_w = (const float*)d_in[1];   // 512 floats
    const float* scale  = (const float*)d_in[2];
    const float* wf     = (const float*)d_in[3];
    float* out = (float*)d_out;
    float* sal = (float*)d_ws;                             // B*HW floats = 401,408 B
    int*   cnt = (int*)((char*)d_ws + (size_t)B * HW * 4); // 64 ints
    int*   cA  = cnt;
    int*   cB  = cnt + 32;

    init_kernel<<<1, 64, 0, stream>>>(cnt);
    fused_kernel<<<B * NPG, 256, 0, stream>>>(x, conv_w, scale, wf, out, sal, cA, cB);
}

// Round 9
// 82.905 us; speedup vs baseline: 3.1365x; 3.1365x over previous
//
#include <hip/hip_runtime.h>
#include <hip/hip_bf16.h>

#define B 32
#define C 512
#define HW 3136            // 56*56 floats per plane
#define HW4 784            // fx4 per plane
#define TH 0.01f
#define NPG 32             // partial groups (blocks per batch)
#define CPB 16             // channels per block

typedef float fx4 __attribute__((ext_vector_type(4)));

// ---------------------------------------------------------------------------
// Kernel A: single-pass partial saliency, quarter-plane per wave.
// Block = (b, pg) owns 16 channels. Each wave owns fx4-cols [196w, 196w+196)
// of EVERY channel: lane l holds 3 fx4 (+ lanes 0-3 a 4th) per channel.
// Per 2-channel group: load quarters (plain cached loads), in-wave reduce to
// quarter-sums, exchange via 16-float LDS (parity slots, 1 barrier), compute
// alphas, FMA into per-wave acc (4 fx4). Epilogue: waves store disjoint
// quarters of the partial plane directly - no cross-wave reduce, no big LDS.
// ~75 VGPR -> 16 waves/CU; x read from HBM exactly once.
// ---------------------------------------------------------------------------
__global__ __launch_bounds__(256, 4) void partial_kernel(const float* __restrict__ x,
                                                         float* __restrict__ out) {
    const int b  = blockIdx.y;
    const int pg = blockIdx.x;          // 0..NPG-1
    const int t  = threadIdx.x;
    const int l  = t & 63;
    const int wv = t >> 6;

    __shared__ float sums[2][2][4];     // [parity][channel][wave]

    const float* __restrict__ xb = x + (size_t)b * C * HW;
    const int qbase = wv * 196;         // this wave's fx4-col base

    fx4 acc0 = (fx4)0.f, acc1 = (fx4)0.f, acc2 = (fx4)0.f, acc3 = (fx4)0.f;

    #pragma unroll 2
    for (int g = 0; g < 8; ++g) {
        const int c0 = pg * CPB + 2 * g;
        const fx4* __restrict__ p0 = (const fx4*)(xb + (size_t)c0 * HW) + qbase + l;
        const fx4* __restrict__ p1 = (const fx4*)(xb + (size_t)(c0 + 1) * HW) + qbase + l;

        const fx4 a0 = p0[0], a1 = p0[64], a2 = p0[128];
        const fx4 b0 = p1[0], b1 = p1[64], b2 = p1[128];
        fx4 a3 = (fx4)0.f, b3 = (fx4)0.f;
        if (l < 4) { a3 = p0[192]; b3 = p1[192]; }

        float sa = (((a0.x + a0.y) + (a0.z + a0.w)) + ((a1.x + a1.y) + (a1.z + a1.w))) +
                   (((a2.x + a2.y) + (a2.z + a2.w)) + ((a3.x + a3.y) + (a3.z + a3.w)));
        float sb = (((b0.x + b0.y) + (b0.z + b0.w)) + ((b1.x + b1.y) + (b1.z + b1.w))) +
                   (((b2.x + b2.y) + (b2.z + b2.w)) + ((b3.x + b3.y) + (b3.z + b3.w)));
        #pragma unroll
        for (int off = 1; off < 64; off <<= 1) {
            sa += __shfl_xor(sa, off);
            sb += __shfl_xor(sb, off);
        }
        if (l == 0) {
            sums[g & 1][0][wv] = sa;
            sums[g & 1][1][wv] = sb;
        }
        __syncthreads();
        const float al0 = ((sums[g & 1][0][0] + sums[g & 1][0][1]) +
                           (sums[g & 1][0][2] + sums[g & 1][0][3])) * (1.0f / (float)HW);
        const float al1 = ((sums[g & 1][1][0] + sums[g & 1][1][1]) +
                           (sums[g & 1][1][2] + sums[g & 1][1][3])) * (1.0f / (float)HW);

        acc0 += a0 * al0 + b0 * al1;
        acc1 += a1 * al0 + b1 * al1;
        acc2 += a2 * al0 + b2 * al1;
        acc3 += a3 * al0 + b3 * al1;
    }

    // direct disjoint store of this wave's quarter (cached; B re-reads it)
    fx4* __restrict__ dst = (fx4*)(out + (size_t)b * C * HW + (size_t)pg * HW) + qbase + l;
    dst[0]   = acc0;
    dst[64]  = acc1;
    dst[128] = acc2;
    if (l < 4) dst[192] = acc3;
}

// ---------------------------------------------------------------------------
// Kernel B: sum 32 partials -> sal, then expansion (R5-verbatim, best known).
// Block = (b, tile of 16 fx4 cols). Partials live in d_out planes co=0..31,
// read before this block overwrites them (read->sync->write within block).
// ---------------------------------------------------------------------------
__global__ __launch_bounds__(256) void out_kernel(const float* __restrict__ w,
                                                  const float* __restrict__ scale_p,
                                                  const float* __restrict__ wf_p,
                                                  float* __restrict__ out) {
    const int b    = blockIdx.y;
    const int tile = blockIdx.x;               // 0..48
    const int t    = threadIdx.x;
    const int hw4  = t & 15;
    const int pg2  = t >> 4;                   // 0..15 -> partials 2*pg2, 2*pg2+1
    const int lane = t & 63;
    const int wid  = t >> 6;

    const fx4* __restrict__ P =
        (const fx4*)(out + (size_t)b * C * HW) + tile * 16 + hw4;
    fx4 s = P[(size_t)(2 * pg2) * HW4] + P[(size_t)(2 * pg2 + 1) * HW4];

    // reduce the 4 pg2-groups in this wave (lane deltas 16, 32)
    s.x += __shfl_xor(s.x, 16); s.y += __shfl_xor(s.y, 16);
    s.z += __shfl_xor(s.z, 16); s.w += __shfl_xor(s.w, 16);
    s.x += __shfl_xor(s.x, 32); s.y += __shfl_xor(s.y, 32);
    s.z += __shfl_xor(s.z, 32); s.w += __shfl_xor(s.w, 32);

    __shared__ fx4 red[4][16];
    if (lane < 16) red[wid][lane] = s;
    __syncthreads();

    __shared__ fx4 sal_sm[16];
    if (t < 16) {
        sal_sm[t] = ((red[0][t] + red[1][t]) + (red[2][t] + red[3][t])) *
                    (1.0f / (float)C);
    }
    __syncthreads();

    const float scale = scale_p[0];
    const float wf    = wf_p[0];
    const float out_zero = 1.0f - 0.5f * wf;   // fm == 0 path
    const fx4 s4 = sal_sm[hw4];

    fx4* __restrict__ ob = (fx4*)(out + (size_t)b * C * HW) + tile * 16 + hw4;
    const int c0 = pg2 * 32;                   // each group covers its 32 co's

    #pragma unroll 4
    for (int k = 0; k < 32; ++k) {
        const int co = c0 + k;
        const float wc = w[co];
        fx4 r;
        float fm;
        fm = s4.x * wc;
        r.x = (fm > TH) ? 1.0f - wf / (1.0f + __expf(-scale * fm)) : out_zero;
        fm = s4.y * wc;
        r.y = (fm > TH) ? 1.0f - wf / (1.0f + __expf(-scale * fm)) : out_zero;
        fm = s4.z * wc;
        r.z = (fm > TH) ? 1.0f - wf / (1.0f + __expf(-scale * fm)) : out_zero;
        fm = s4.w * wc;
        r.w = (fm > TH) ? 1.0f - wf / (1.0f + __expf(-scale * fm)) : out_zero;
        __builtin_nontemporal_store(r, ob + (size_t)co * HW4);
    }
}

extern "C" void kernel_launch(void* const* d_in, const int* in_sizes, int n_in,
                              void* d_out, int out_size, void* d_ws, size_t ws_size,
                              hipStream_t stream) {
    const float* x      = (const float*)d_in[0];
    const float* conv_w = (const float*)d_in[1];   // 512 floats
    const float* scale  = (const float*)d_in[2];
    const float* wf     = (const float*)d_in[3];
    float* out = (float*)d_out;

    dim3 gridA(NPG, B);                            // 32 x 32 = 1024 blocks
    partial_kernel<<<gridA, 256, 0, stream>>>(x, out);

    dim3 gridB(HW4 / 16, B);                       // 49 x 32 = 1568 blocks
    out_kernel<<<gridB, 256, 0, stream>>>(conv_w, scale, wf, out);
}